// Round 12
// baseline (58.644 us; speedup 1.0000x reference)
//
#include <hip/hip_runtime.h>
#include <math.h>

namespace {
constexpr int kB = 256;
constexpr int kT = 64;
constexpr int kPhys = 3;
constexpr int kLat = 8;
constexpr int kNN = 128;
constexpr int kWin = 32;
constexpr int kPred = 64;
constexpr int kHRow = 132;
constexpr int kThreads = 1024;
constexpr int kWUnit = 8 * 4 * 64 * 8;  // 16384 shorts per weight plane-unit
}

typedef short bf16x8 __attribute__((ext_vector_type(8)));
typedef float f32x4 __attribute__((ext_vector_type(4)));

__device__ __forceinline__ double rdlane_f64(double x, int l) {
  const long long v = __double_as_longlong(x);
  const int lo = __builtin_amdgcn_readlane((int)(unsigned int)(v & 0xffffffffll), l);
  const int hi = __builtin_amdgcn_readlane((int)(v >> 32), l);
  const long long r = (((long long)hi) << 32) | (unsigned long long)(unsigned int)lo;
  return __longlong_as_double(r);
}

__device__ __forceinline__ unsigned rneb(float f) {  // f32 -> bf16 bits (RNE)
  const unsigned u = __float_as_uint(f);
  return (u + 0x7fffu + ((u >> 16) & 1u)) >> 16;
}
__device__ __forceinline__ void split3(float a, short& s1, short& s2, short& s3) {
  const unsigned b1 = rneb(a);
  const float f1 = __uint_as_float(b1 << 16);
  const float r1 = a - f1;
  const unsigned b2 = rneb(r1);
  const float f2 = __uint_as_float(b2 << 16);
  s1 = (short)b1; s2 = (short)b2; s3 = (short)rneb(r1 - f2);
}
__device__ __forceinline__ void split2(float a, short& s1, short& s2) {
  const unsigned b1 = rneb(a);
  const float f1 = __uint_as_float(b1 << 16);
  s1 = (short)b1; s2 = (short)rneb(a - f1);
}

struct B4 { bf16x8 v[4]; };  // one B-fragment plane (4 q-slices)
__device__ __forceinline__ void loadPlane(B4& d, const short* __restrict__ plane,
                                          int n, int l) {
#pragma unroll
  for (int q = 0; q < 4; ++q)
    d.v[q] = *(const bf16x8*)&plane[((n * 4 + q) * 64 + l) * 8];
}

// ---- prologue: split hidden weights into B-fragment planes (launch-invariant) ----
__global__ __launch_bounds__(256) void split_weights_kernel(
    const float* __restrict__ ewh, const float* __restrict__ dwh,
    short* __restrict__ wfrag)
{
  const int gid = blockIdx.x * 256 + threadIdx.x;  // 12288
  const int l = gid & 63;
  const int q = (gid >> 6) & 3;
  const int n = (gid >> 8) & 7;
  const int layer = gid >> 11;  // 0..5
  const bool enc = layer < 3;
  const float* __restrict__ W = enc ? (ewh + (size_t)layer * kNN * kNN)
                                    : (dwh + (size_t)(layer - 3) * kNN * kNN);
  const int colg = 16 * n + (l & 15);
  const int krow = 8 * (l >> 4);
  bf16x8 p1, p2, p3;
#pragma unroll
  for (int e = 0; e < 8; ++e) {
    const float wv = W[(32 * q + krow + e) * kNN + colg];
    short s1, s2, s3; split3(wv, s1, s2, s3);
    p1[e] = s1; p2[e] = s2; p3[e] = s3;
  }
  const int off = ((n * 4 + q) * 64 + l) * 8;
  if (enc) {
    const size_t base = (size_t)(layer * 3) * kWUnit;
    *(bf16x8*)&wfrag[base + off] = p1;
    *(bf16x8*)&wfrag[base + kWUnit + off] = p2;
    *(bf16x8*)&wfrag[base + 2 * kWUnit + off] = p3;
  } else {
    const size_t base = (size_t)(9 + (layer - 3) * 2) * kWUnit;
    *(bf16x8*)&wfrag[base + off] = p1;
    *(bf16x8*)&wfrag[base + kWUnit + off] = p2;
  }
}

// ---- encoder hidden layer (16 waves: n = w&7, m0 = (w>>3)*2), B preloaded ----
template<bool TO_FRAG>
__device__ __forceinline__ void mfma_enc3(
    const B4& b1, const B4& b2, const B4& b3, const float* __restrict__ bias,
    const short* __restrict__ fragIn, void* __restrict__ out, int tid)
{
  constexpr int PLANE = 4 * 4 * 64 * 8;
  const int w = tid >> 6, l = tid & 63;
  const int n = w & 7, m0 = (w >> 3) * 2;
  const int colg = 16 * n + (l & 15);
  const float bj = bias[colg];
  f32x4 acc[2];
#pragma unroll
  for (int mi = 0; mi < 2; ++mi) acc[mi] = {bj, bj, bj, bj};
#pragma unroll
  for (int q = 0; q < 4; ++q) {
#pragma unroll
    for (int mi = 0; mi < 2; ++mi) {
      const int o = (((m0 + mi) * 4 + q) * 64 + l) * 8;
      const bf16x8 a1 = *(const bf16x8*)&fragIn[o];
      const bf16x8 a2 = *(const bf16x8*)&fragIn[PLANE + o];
      const bf16x8 a3 = *(const bf16x8*)&fragIn[2 * PLANE + o];
      acc[mi] = __builtin_amdgcn_mfma_f32_16x16x32_bf16(a1, b1.v[q], acc[mi], 0, 0, 0);
      acc[mi] = __builtin_amdgcn_mfma_f32_16x16x32_bf16(a1, b2.v[q], acc[mi], 0, 0, 0);
      acc[mi] = __builtin_amdgcn_mfma_f32_16x16x32_bf16(a2, b1.v[q], acc[mi], 0, 0, 0);
      acc[mi] = __builtin_amdgcn_mfma_f32_16x16x32_bf16(a1, b3.v[q], acc[mi], 0, 0, 0);
      acc[mi] = __builtin_amdgcn_mfma_f32_16x16x32_bf16(a2, b2.v[q], acc[mi], 0, 0, 0);
      acc[mi] = __builtin_amdgcn_mfma_f32_16x16x32_bf16(a3, b1.v[q], acc[mi], 0, 0, 0);
    }
  }
  const int rbase = (l >> 4) * 4;
  if constexpr (TO_FRAG) {
    short* __restrict__ f = (short*)out;
    const int qt = colg >> 5, sub = (colg >> 3) & 3, et = colg & 7;
#pragma unroll
    for (int mi = 0; mi < 2; ++mi)
#pragma unroll
      for (int r = 0; r < 4; ++r) {
        const float v = fmaxf(acc[mi][r], 0.f);
        const int off = (((m0 + mi) * 4 + qt) * 64 + (rbase + r + 16 * sub)) * 8 + et;
        short s1, s2, s3; split3(v, s1, s2, s3);
        f[off] = s1; f[PLANE + off] = s2; f[2 * PLANE + off] = s3;
      }
  } else {
    float* __restrict__ hb = (float*)out;
#pragma unroll
    for (int mi = 0; mi < 2; ++mi)
#pragma unroll
      for (int r = 0; r < 4; ++r)
        hb[(16 * (m0 + mi) + rbase + r) * kHRow + colg] = fmaxf(acc[mi][r], 0.f);
  }
}

// ---- decoder layer on 8 waves (n given), MTN m-tiles, 2-split, B preloaded ----
template<int MTN, bool TO_FRAG>
__device__ __forceinline__ void mfma_dec2(
    const B4& b1, const B4& b2, const float* __restrict__ bias,
    const short* __restrict__ fragIn, void* __restrict__ out, int n, int l)
{
  constexpr int PLANE = MTN * 4 * 64 * 8;
  const int colg = 16 * n + (l & 15);
  const float bj = bias[colg];
  f32x4 acc[MTN];
#pragma unroll
  for (int mi = 0; mi < MTN; ++mi) acc[mi] = {bj, bj, bj, bj};
#pragma unroll
  for (int q = 0; q < 4; ++q) {
#pragma unroll
    for (int mi = 0; mi < MTN; ++mi) {
      const int o = ((mi * 4 + q) * 64 + l) * 8;
      const bf16x8 a1 = *(const bf16x8*)&fragIn[o];
      const bf16x8 a2 = *(const bf16x8*)&fragIn[PLANE + o];
      acc[mi] = __builtin_amdgcn_mfma_f32_16x16x32_bf16(a1, b1.v[q], acc[mi], 0, 0, 0);
      acc[mi] = __builtin_amdgcn_mfma_f32_16x16x32_bf16(a1, b2.v[q], acc[mi], 0, 0, 0);
      acc[mi] = __builtin_amdgcn_mfma_f32_16x16x32_bf16(a2, b1.v[q], acc[mi], 0, 0, 0);
    }
  }
  const int rbase = (l >> 4) * 4;
  if constexpr (TO_FRAG) {
    short* __restrict__ f = (short*)out;
    const int qt = colg >> 5, sub = (colg >> 3) & 3, et = colg & 7;
#pragma unroll
    for (int mi = 0; mi < MTN; ++mi)
#pragma unroll
      for (int r = 0; r < 4; ++r) {
        const float v = fmaxf(acc[mi][r], 0.f);
        const int off = ((mi * 4 + qt) * 64 + (rbase + r + 16 * sub)) * 8 + et;
        short s1, s2; split2(v, s1, s2);
        f[off] = s1; f[PLANE + off] = s2;
      }
  } else {
    float* __restrict__ hb = (float*)out;
#pragma unroll
    for (int mi = 0; mi < MTN; ++mi)
#pragma unroll
      for (int r = 0; r < 4; ++r)
        hb[(16 * mi + rbase + r) * kHRow + colg] = fmaxf(acc[mi][r], 0.f);
  }
}

__global__ __launch_bounds__(kThreads, 4) void fused_kernel(
    const float* __restrict__ x,
    const float* __restrict__ ewin, const float* __restrict__ ebin,
    const float* __restrict__ ebh,
    const float* __restrict__ ewout,const float* __restrict__ ebout,
    const float* __restrict__ dwin, const float* __restrict__ dbin,
    const float* __restrict__ dbh,
    const float* __restrict__ dwout,const float* __restrict__ dbout,
    const short* __restrict__ wfrag,
    float* __restrict__ y_g, float* __restrict__ xae_g,
    float* __restrict__ xadv_g, float* __restrict__ yadv_g)
{
  __shared__ __align__(16) char bufA[50688];
  __shared__ __align__(16) char bufB[50688];
  __shared__ __align__(16) double dmdS[5280];
  __shared__ float ybuf[512];
  __shared__ float yadv2[256];
  __shared__ float xstash[192];

  double* P    = dmdS;          // [32][67]
  double* Corr = dmdS + 2144;   // [32][33]
  double* KTm  = dmdS + 3200;   // [31][33]
  double* Dv   = dmdS + 4223;   // [32][33]

  short* fragA_G1 = (short*)bufA;               // 32768 B (2 planes, MTN=4)
  short* fragA_G2 = (short*)(bufA + 32768);     // 16384 B (2 planes, MTN=2)
  short* fragB_G1 = (short*)bufB;
  short* fragB_G2 = (short*)(bufB + 33792);
  float* hbB_G1   = (float*)bufB;               // [64][132] f32
  float* hbA_G2   = (float*)bufA;               // [32][132] f32

  const short* wE0 = wfrag;
  const short* wE1 = wfrag + (size_t)3 * kWUnit;
  const short* wE2 = wfrag + (size_t)6 * kWUnit;
  const short* wD0 = wfrag + (size_t)9 * kWUnit;
  const short* wD1 = wfrag + (size_t)11 * kWUnit;
  const short* wD2 = wfrag + (size_t)13 * kWUnit;

  const int tid = threadIdx.x;
  const int l64 = tid & 63;
  const int nE = (tid >> 6) & 7;        // encoder n-tile
  const int nD = (tid >> 6) - 8;        // decoder n-tile (waves 8..15)
  const int b = blockIdx.x;

  B4 S0p1, S0p2, S1p1, S1p2, T;         // encoder B sets
  B4 C0p1, C0p2, C1p1, C1p2;            // decoder B sets (waves 8..15)

  // ======== ph1: encoder input scatter -> bufA; prefetch enc L0 B ========
  {
    constexpr int PE = 4 * 4 * 64 * 8;
    short* __restrict__ f = (short*)bufA;
    const float* __restrict__ xg = x + (size_t)b * kT * kPhys;
    const int j = tid & 127, rg = tid >> 7;
    const float w0 = ewin[j], w1 = ewin[kNN + j], w2 = ewin[2 * kNN + j];
    const float bj = ebin[j];
    const int qt = j >> 5, sub = (j >> 3) & 3, et = j & 7;
    loadPlane(S0p1, wE0, nE, l64);
    loadPlane(S0p2, wE0 + kWUnit, nE, l64);
    loadPlane(T, wE0 + 2 * kWUnit, nE, l64);
#pragma unroll
    for (int rr = 0; rr < 8; ++rr) {
      const int r = rg * 8 + rr;
      const float* __restrict__ xr = xg + r * 3;
      const float a = fmaxf(bj + xr[0] * w0 + xr[1] * w1 + xr[2] * w2, 0.f);
      short s1, s2, s3; split3(a, s1, s2, s3);
      const int off = (((r >> 4) * 4 + qt) * 64 + ((r & 15) + 16 * sub)) * 8 + et;
      f[off] = s1; f[PE + off] = s2; f[2 * PE + off] = s3;
    }
  }
  __syncthreads();

  // ======== ph2: enc L0 (B=S0,T); prefetch L1 ========
  loadPlane(S1p1, wE1, nE, l64);
  loadPlane(S1p2, wE1 + kWUnit, nE, l64);
  mfma_enc3<true>(S0p1, S0p2, T, ebh + 0 * kNN, (short*)bufA, bufB, tid);
  loadPlane(T, wE1 + 2 * kWUnit, nE, l64);
  __syncthreads();

  // ======== ph3: enc L1 (B=S1,T); prefetch L2 ========
  loadPlane(S0p1, wE2, nE, l64);
  loadPlane(S0p2, wE2 + kWUnit, nE, l64);
  mfma_enc3<true>(S1p1, S1p2, T, ebh + 1 * kNN, (short*)bufB, bufA, tid);
  loadPlane(T, wE2 + 2 * kWUnit, nE, l64);
  __syncthreads();

  // ======== ph4: enc L2 -> natural hb (bufB) ========
  mfma_enc3<false>(S0p1, S0p2, T, ebh + 2 * kNN, (short*)bufA, bufB, tid);
  __syncthreads();

  // ======== ph5: enc out 128->8 -> ybuf (waves 0..7) | prefetch dec L0 (8..15) ====
  if (tid < 512) {
    const float* __restrict__ hb = (const float*)bufB;
    const int r = tid >> 3, o = tid & 7;
    float a = ebout[o];
    for (int k4 = 0; k4 < kNN; k4 += 4) {
      const float4 hv = *(const float4*)&hb[r * kHRow + k4];
      a += hv.x * ewout[(k4 + 0) * kLat + o] + hv.y * ewout[(k4 + 1) * kLat + o]
         + hv.z * ewout[(k4 + 2) * kLat + o] + hv.w * ewout[(k4 + 3) * kLat + o];
    }
    ybuf[tid] = a;
  } else {
    loadPlane(C0p1, wD0, nD, l64);
    loadPlane(C0p2, wD0 + kWUnit, nD, l64);
  }
  __syncthreads();

  // ======== ph6: P (waves 0..7) || dec G1 input scatter rows 0..63 (8..15) ========
  if (tid < 512) {
    for (int idx = tid; idx < 32 * 64; idx += 512) {
      const int d = idx >> 6, t = idx & 63;
      if (t + d < kT) {
        double s = 0.0;
#pragma unroll
        for (int l = 0; l < kLat; ++l)
          s += (double)ybuf[t * 8 + l] * (double)ybuf[(t + d) * 8 + l];
        P[d * 67 + t] = s;
      }
    }
  } else {
    constexpr int PD = 4 * 4 * 64 * 8;
    short* __restrict__ f = fragA_G1;
    const int j = tid & 127, rg = (tid >> 7) - 4;
    float wr[kLat];
#pragma unroll
    for (int k = 0; k < kLat; ++k) wr[k] = dwin[k * kNN + j];
    const float bj = dbin[j];
    const int qt = j >> 5, sub = (j >> 3) & 3, et = j & 7;
#pragma unroll
    for (int rr = 0; rr < 16; ++rr) {
      const int r = rg * 16 + rr;
      const float* __restrict__ src = &ybuf[r * kLat];
      float a = bj;
#pragma unroll
      for (int k = 0; k < kLat; ++k) a += src[k] * wr[k];
      a = fmaxf(a, 0.f);
      short s1, s2; split2(a, s1, s2);
      const int off = (((r >> 4) * 4 + qt) * 64 + ((r & 15) + 16 * sub)) * 8 + et;
      f[off] = s1; f[PD + off] = s2;
    }
  }
  __syncthreads();

  // ======== ph7: Corr (all 1024) ========
  {
    const int a = tid >> 5, c = tid & 31;
    const int d = (c >= a) ? (c - a) : (a - c);
    const int base = (c >= a) ? a : c;
    double s0 = 0.0, s1 = 0.0;
#pragma unroll
    for (int r = 0; r < 32; r += 2) { s0 += P[d * 67 + base + r]; s1 += P[d * 67 + base + r + 1]; }
    Corr[a * 33 + c] = s0 + s1 + P[d * 67 + base + 32];
  }
  __syncthreads();

  // ======== ph8: GJ+power (wave 0) || dec L0 G1 (waves 8..15, prefetch L1) ========
  if (tid < 64) {
    const int lane = tid;
    const int colidx = (lane <= 30) ? lane : (lane <= 61 ? lane - 30 : 1);
    double m[31];
#pragma unroll
    for (int i = 0; i < 31; ++i) m[i] = Corr[i * 33 + colidx];
#pragma unroll
    for (int k = 0; k < 31; ++k) {
      const double piv = rdlane_f64(m[k], k);
      const double pinv = 1.0 / piv;
      m[k] *= pinv;
#pragma unroll
      for (int i = 0; i < 31; ++i) {
        if (i == k) continue;
        const double bci = rdlane_f64(m[i], k);
        m[i] = fma(-bci, m[k], m[i]);
      }
    }
    if (lane >= 31 && lane < 62) {
      const int c = lane - 31;
#pragma unroll
      for (int i = 0; i < 31; ++i) KTm[i * 33 + c] = m[i];
    }
    const int ri = (lane < 31) ? lane : 0;
    double Kr[31];
#pragma unroll
    for (int j = 0; j < 31; ++j) Kr[j] = KTm[ri * 33 + j];
    double dv = Kr[30];
    if (lane < 31) Dv[0 * 33 + lane] = dv;
    for (int k = 0; k < 31; ++k) {
      double a0 = 0.0, a1 = 0.0, a2 = 0.0, a3 = 0.0;
#pragma unroll
      for (int j = 0; j < 31; ++j) {
        const double dj = rdlane_f64(dv, j);
        if ((j & 3) == 0) a0 = fma(Kr[j], dj, a0);
        else if ((j & 3) == 1) a1 = fma(Kr[j], dj, a1);
        else if ((j & 3) == 2) a2 = fma(Kr[j], dj, a2);
        else a3 = fma(Kr[j], dj, a3);
      }
      dv = (a0 + a1) + (a2 + a3);
      if (lane < 31) Dv[(k + 1) * 33 + lane] = dv;
    }
  } else if (tid >= 512) {
    loadPlane(C1p1, wD1, nD, l64);
    loadPlane(C1p2, wD1 + kWUnit, nD, l64);
    mfma_dec2<4, true>(C0p1, C0p2, dbh + 0 * kNN, fragA_G1, fragB_G1, nD, l64);
  }
  __syncthreads();

  // ======== ph9: yadv2 (tid<256) || dec L1 G1 (waves 8..15, prefetch L2) ========
  if (tid < 256) {
    const int k = tid >> 3, l = tid & 7;
    double a0 = 0.0, a1 = 0.0, a2 = 0.0, a3 = 0.0;
#pragma unroll
    for (int j = 0; j < 31; ++j) {
      const double t = (double)ybuf[(j + 1) * 8 + l];
      if ((j & 3) == 0) a0 = fma(t, Dv[k * 33 + j], a0);
      else if ((j & 3) == 1) a1 = fma(t, Dv[k * 33 + j], a1);
      else if ((j & 3) == 2) a2 = fma(t, Dv[k * 33 + j], a2);
      else a3 = fma(t, Dv[k * 33 + j], a3);
    }
    yadv2[tid] = (float)((a0 + a1) + (a2 + a3));
  } else if (tid >= 512) {
    loadPlane(C0p1, wD2, nD, l64);
    loadPlane(C0p2, wD2 + kWUnit, nD, l64);
    mfma_dec2<4, true>(C1p1, C1p2, dbh + 1 * kNN, fragB_G1, fragA_G1, nD, l64);
  }
  __syncthreads();

  // ======== ph10: G2 scatter rows 64..95 (waves 0..7) || dec L2 G1 -> hbB (8..15) ==
  if (tid < 512) {
    constexpr int PD = 2 * 4 * 64 * 8;
    short* __restrict__ f = fragA_G2;
    const int j = tid & 127, rg = tid >> 7;  // 4 groups x 8 rows
    float wr[kLat];
#pragma unroll
    for (int k = 0; k < kLat; ++k) wr[k] = dwin[k * kNN + j];
    const float bj = dbin[j];
    const int qt = j >> 5, sub = (j >> 3) & 3, et = j & 7;
#pragma unroll
    for (int rr = 0; rr < 8; ++rr) {
      const int r = 64 + rg * 8 + rr;  // 64..95
      const float* __restrict__ src = &yadv2[(r - kT) * kLat];
      float a = bj;
#pragma unroll
      for (int k = 0; k < kLat; ++k) a += src[k] * wr[k];
      a = fmaxf(a, 0.f);
      short s1, s2; split2(a, s1, s2);
      const int mi = (r - 64) >> 4;
      const int off = ((mi * 4 + qt) * 64 + ((r & 15) + 16 * sub)) * 8 + et;
      f[off] = s1; f[PD + off] = s2;
    }
  } else {
    loadPlane(C1p1, wD0, nD, l64);
    loadPlane(C1p2, wD0 + kWUnit, nD, l64);
    mfma_dec2<4, false>(C0p1, C0p2, dbh + 2 * kNN, fragA_G1, hbB_G1, nD, l64);
  }
  __syncthreads();

  // ======== ph11: G1 out -> xstash (tid<192) || dec L0 G2 (waves 8..15) ========
  if (tid < 192) {
    const int r = tid / 3, o = tid - r * 3;
    float a = dbout[o];
    for (int k4 = 0; k4 < kNN; k4 += 4) {
      const float4 hv = *(const float4*)&hbB_G1[r * kHRow + k4];
      a += hv.x * dwout[(k4 + 0) * kPhys + o] + hv.y * dwout[(k4 + 1) * kPhys + o]
         + hv.z * dwout[(k4 + 2) * kPhys + o] + hv.w * dwout[(k4 + 3) * kPhys + o];
    }
    xstash[tid] = a;
  } else if (tid >= 512) {
    loadPlane(C0p1, wD1, nD, l64);
    loadPlane(C0p2, wD1 + kWUnit, nD, l64);
    mfma_dec2<2, true>(C1p1, C1p2, dbh + 0 * kNN, fragA_G2, fragB_G2, nD, l64);
  }
  __syncthreads();

  // ======== ph12: y/yadv global stores (tid<512) || dec L1 G2 (waves 8..15) ========
  if (tid < 512) {
    y_g[(size_t)b * kT * kLat + tid] = ybuf[tid];
    yadv_g[(size_t)b * kPred * kLat + tid] = (tid < 256) ? ybuf[tid] : yadv2[tid - 256];
  } else {
    loadPlane(C1p1, wD2, nD, l64);
    loadPlane(C1p2, wD2 + kWUnit, nD, l64);
    mfma_dec2<2, true>(C0p1, C0p2, dbh + 1 * kNN, fragB_G2, fragA_G2, nD, l64);
  }
  __syncthreads();

  // ======== ph13: dec L2 G2 -> hbA (waves 8..15) ========
  if (tid >= 512) {
    mfma_dec2<2, false>(C1p1, C1p2, dbh + 2 * kNN, fragA_G2, hbA_G2, nD, l64);
  }
  __syncthreads();

  // ======== ph14 (final, no barrier): G2 out + x stores ========
  if (tid < 96) {
    const int r = tid / 3, o = tid - r * 3;  // local row 0..31 (global 64+r)
    float a = dbout[o];
    for (int k4 = 0; k4 < kNN; k4 += 4) {
      const float4 hv = *(const float4*)&hbA_G2[r * kHRow + k4];
      a += hv.x * dwout[(k4 + 0) * kPhys + o] + hv.y * dwout[(k4 + 1) * kPhys + o]
         + hv.z * dwout[(k4 + 2) * kPhys + o] + hv.w * dwout[(k4 + 3) * kPhys + o];
    }
    xadv_g[(size_t)b * kT * kPhys + (r + 32) * kPhys + o] = a;
  } else if (tid < 288) {
    const int i = tid - 96;
    xae_g[(size_t)b * kT * kPhys + i] = xstash[i];
  } else if (tid < 384) {
    const int i = tid - 288;
    xadv_g[(size_t)b * kT * kPhys + i] = xstash[i];
  }
}

extern "C" void kernel_launch(void* const* d_in, const int* in_sizes, int n_in,
                              void* d_out, int out_size, void* d_ws, size_t ws_size,
                              hipStream_t stream)
{
  const float* x         = (const float*)d_in[0];
  const float* enc_w_in  = (const float*)d_in[1];
  const float* enc_b_in  = (const float*)d_in[2];
  const float* enc_w_h   = (const float*)d_in[3];
  const float* enc_b_h   = (const float*)d_in[4];
  const float* enc_w_out = (const float*)d_in[5];
  const float* enc_b_out = (const float*)d_in[6];
  const float* dec_w_in  = (const float*)d_in[7];
  const float* dec_b_in  = (const float*)d_in[8];
  const float* dec_w_h   = (const float*)d_in[9];
  const float* dec_b_h   = (const float*)d_in[10];
  const float* dec_w_out = (const float*)d_in[11];
  const float* dec_b_out = (const float*)d_in[12];

  float* out   = (float*)d_out;
  float* y     = out;                                  // (B,T,8)   131072
  float* x_ae  = out + (size_t)kB * kT * kLat;         // (B,T,3)    49152
  float* x_adv = x_ae + (size_t)kB * kT * kPhys;       // (B,T,3)    49152
  float* y_adv = x_adv + (size_t)kB * kT * kPhys;      // (B,64,8)  131072

  short* wfrag = (short*)d_ws;   // 15 units x 16384 shorts = 491520 B

  split_weights_kernel<<<48, 256, 0, stream>>>(enc_w_h, dec_w_h, wfrag);
  fused_kernel<<<kB, kThreads, 0, stream>>>(
      x, enc_w_in, enc_b_in, enc_b_h, enc_w_out, enc_b_out,
      dec_w_in, dec_b_in, dec_b_h, dec_w_out, dec_b_out,
      wfrag, y, x_ae, x_adv, y_adv);
}

// Round 13
// 55.007 us; speedup vs baseline: 1.0661x; 1.0661x over previous
//
#include <hip/hip_runtime.h>
#include <math.h>

namespace {
constexpr int kB = 256;
constexpr int kT = 64;
constexpr int kPhys = 3;
constexpr int kLat = 8;
constexpr int kNN = 128;
constexpr int kWin = 32;
constexpr int kPred = 64;
constexpr int kHRow = 132;
constexpr int kThreads = 1024;
constexpr int kWUnit = 8 * 4 * 64 * 8;  // 16384 shorts per weight plane-unit
}

typedef short bf16x8 __attribute__((ext_vector_type(8)));
typedef float f32x4 __attribute__((ext_vector_type(4)));

// XOR swizzle of the fragment storage-unit low 6 bits (involution; bit-exact).
// Kills the 8/16-way bank conflicts on b16 fragment scatter stores while
// keeping b128 fragment reads conflict-free (bijection within 64-unit window).
__device__ __forceinline__ int swz(int L) { return L ^ ((L >> 3) & 7); }

__device__ __forceinline__ double rdlane_f64(double x, int l) {
  const long long v = __double_as_longlong(x);
  const int lo = __builtin_amdgcn_readlane((int)(unsigned int)(v & 0xffffffffll), l);
  const int hi = __builtin_amdgcn_readlane((int)(v >> 32), l);
  const long long r = (((long long)hi) << 32) | (unsigned long long)(unsigned int)lo;
  return __longlong_as_double(r);
}

__device__ __forceinline__ unsigned rneb(float f) {  // f32 -> bf16 bits (RNE)
  const unsigned u = __float_as_uint(f);
  return (u + 0x7fffu + ((u >> 16) & 1u)) >> 16;
}
__device__ __forceinline__ void split3(float a, short& s1, short& s2, short& s3) {
  const unsigned b1 = rneb(a);
  const float f1 = __uint_as_float(b1 << 16);
  const float r1 = a - f1;
  const unsigned b2 = rneb(r1);
  const float f2 = __uint_as_float(b2 << 16);
  s1 = (short)b1; s2 = (short)b2; s3 = (short)rneb(r1 - f2);
}
__device__ __forceinline__ void split2(float a, short& s1, short& s2) {
  const unsigned b1 = rneb(a);
  const float f1 = __uint_as_float(b1 << 16);
  s1 = (short)b1; s2 = (short)rneb(a - f1);
}

// ---- prologue: split hidden weights into B-fragment planes (launch-invariant) ----
__global__ __launch_bounds__(256) void split_weights_kernel(
    const float* __restrict__ ewh, const float* __restrict__ dwh,
    short* __restrict__ wfrag)
{
  const int gid = blockIdx.x * 256 + threadIdx.x;  // 12288
  const int l = gid & 63;
  const int q = (gid >> 6) & 3;
  const int n = (gid >> 8) & 7;
  const int layer = gid >> 11;  // 0..5
  const bool enc = layer < 3;
  const float* __restrict__ W = enc ? (ewh + (size_t)layer * kNN * kNN)
                                    : (dwh + (size_t)(layer - 3) * kNN * kNN);
  const int colg = 16 * n + (l & 15);
  const int krow = 8 * (l >> 4);
  bf16x8 p1, p2, p3;
#pragma unroll
  for (int e = 0; e < 8; ++e) {
    const float wv = W[(32 * q + krow + e) * kNN + colg];
    short s1, s2, s3; split3(wv, s1, s2, s3);
    p1[e] = s1; p2[e] = s2; p3[e] = s3;
  }
  const int off = ((n * 4 + q) * 64 + l) * 8;
  if (enc) {
    const size_t base = (size_t)(layer * 3) * kWUnit;
    *(bf16x8*)&wfrag[base + off] = p1;
    *(bf16x8*)&wfrag[base + kWUnit + off] = p2;
    *(bf16x8*)&wfrag[base + 2 * kWUnit + off] = p3;
  } else {
    const size_t base = (size_t)(9 + (layer - 3) * 2) * kWUnit;
    *(bf16x8*)&wfrag[base + off] = p1;
    *(bf16x8*)&wfrag[base + kWUnit + off] = p2;
  }
}

// ---- encoder hidden layer (16 waves: n = w&7, m-group = w>>3) ----
template<int MPW, int SPLITS, bool TO_FRAG>
__device__ __forceinline__ void mfma_enc(
    const short* __restrict__ Bfrag, const float* __restrict__ bias,
    const short* __restrict__ fragIn, void* __restrict__ out, int tid)
{
  constexpr int MT = 2 * MPW;
  constexpr int PLANE = MT * 4 * 64 * 8;
  const int w = tid >> 6, l = tid & 63;
  const int n = w & 7, m0 = (w >> 3) * MPW;
  const int colg = 16 * n + (l & 15);
  const int ls = swz(l);
  bf16x8 B1[4], B2[4], B3[4];
#pragma unroll
  for (int q = 0; q < 4; ++q) {
    const int boff = ((n * 4 + q) * 64 + l) * 8;
    B1[q] = *(const bf16x8*)&Bfrag[boff];
    B2[q] = *(const bf16x8*)&Bfrag[kWUnit + boff];
    if constexpr (SPLITS == 3) B3[q] = *(const bf16x8*)&Bfrag[2 * kWUnit + boff];
  }
  const float bj = bias[colg];
  f32x4 acc[MPW];
#pragma unroll
  for (int mi = 0; mi < MPW; ++mi) acc[mi] = {bj, bj, bj, bj};
#pragma unroll
  for (int q = 0; q < 4; ++q) {
#pragma unroll
    for (int mi = 0; mi < MPW; ++mi) {
      const int o = (((m0 + mi) * 4 + q) * 64 + ls) * 8;
      const bf16x8 a1 = *(const bf16x8*)&fragIn[o];
      const bf16x8 a2 = *(const bf16x8*)&fragIn[PLANE + o];
      acc[mi] = __builtin_amdgcn_mfma_f32_16x16x32_bf16(a1, B1[q], acc[mi], 0, 0, 0);
      acc[mi] = __builtin_amdgcn_mfma_f32_16x16x32_bf16(a1, B2[q], acc[mi], 0, 0, 0);
      acc[mi] = __builtin_amdgcn_mfma_f32_16x16x32_bf16(a2, B1[q], acc[mi], 0, 0, 0);
      if constexpr (SPLITS == 3) {
        const bf16x8 a3 = *(const bf16x8*)&fragIn[2 * PLANE + o];
        acc[mi] = __builtin_amdgcn_mfma_f32_16x16x32_bf16(a1, B3[q], acc[mi], 0, 0, 0);
        acc[mi] = __builtin_amdgcn_mfma_f32_16x16x32_bf16(a2, B2[q], acc[mi], 0, 0, 0);
        acc[mi] = __builtin_amdgcn_mfma_f32_16x16x32_bf16(a3, B1[q], acc[mi], 0, 0, 0);
      }
    }
  }
  const int rbase = (l >> 4) * 4;
  if constexpr (TO_FRAG) {
    short* __restrict__ f = (short*)out;
    const int qt = colg >> 5, sub = (colg >> 3) & 3, et = colg & 7;
#pragma unroll
    for (int mi = 0; mi < MPW; ++mi)
#pragma unroll
      for (int r = 0; r < 4; ++r) {
        const float v = fmaxf(acc[mi][r], 0.f);
        const int off = (((m0 + mi) * 4 + qt) * 64 + swz(rbase + r + 16 * sub)) * 8 + et;
        short s1, s2, s3; split3(v, s1, s2, s3);
        f[off] = s1; f[PLANE + off] = s2; f[2 * PLANE + off] = s3;
      }
  } else {
    float* __restrict__ hb = (float*)out;
#pragma unroll
    for (int mi = 0; mi < MPW; ++mi)
#pragma unroll
      for (int r = 0; r < 4; ++r)
        hb[(16 * (m0 + mi) + rbase + r) * kHRow + colg] = fmaxf(acc[mi][r], 0.f);
  }
}

// ---- decoder tile-set layer (8 waves; wave handles all MTN m-tiles, 2-split) ----
template<int MTN, bool TO_FRAG>
__device__ __forceinline__ void mfma_dec(
    const short* __restrict__ Bfrag, const float* __restrict__ bias,
    const short* __restrict__ fragIn, void* __restrict__ out, int n, int l)
{
  constexpr int PLANE = MTN * 4 * 64 * 8;
  const int colg = 16 * n + (l & 15);
  const int ls = swz(l);
  bf16x8 B1[4], B2[4];
#pragma unroll
  for (int q = 0; q < 4; ++q) {
    const int boff = ((n * 4 + q) * 64 + l) * 8;
    B1[q] = *(const bf16x8*)&Bfrag[boff];
    B2[q] = *(const bf16x8*)&Bfrag[kWUnit + boff];
  }
  const float bj = bias[colg];
  f32x4 acc[MTN];
#pragma unroll
  for (int mi = 0; mi < MTN; ++mi) acc[mi] = {bj, bj, bj, bj};
#pragma unroll
  for (int q = 0; q < 4; ++q) {
#pragma unroll
    for (int mi = 0; mi < MTN; ++mi) {
      const int o = ((mi * 4 + q) * 64 + ls) * 8;
      const bf16x8 a1 = *(const bf16x8*)&fragIn[o];
      const bf16x8 a2 = *(const bf16x8*)&fragIn[PLANE + o];
      acc[mi] = __builtin_amdgcn_mfma_f32_16x16x32_bf16(a1, B1[q], acc[mi], 0, 0, 0);
      acc[mi] = __builtin_amdgcn_mfma_f32_16x16x32_bf16(a1, B2[q], acc[mi], 0, 0, 0);
      acc[mi] = __builtin_amdgcn_mfma_f32_16x16x32_bf16(a2, B1[q], acc[mi], 0, 0, 0);
    }
  }
  const int rbase = (l >> 4) * 4;
  if constexpr (TO_FRAG) {
    short* __restrict__ f = (short*)out;
    const int qt = colg >> 5, sub = (colg >> 3) & 3, et = colg & 7;
#pragma unroll
    for (int mi = 0; mi < MTN; ++mi)
#pragma unroll
      for (int r = 0; r < 4; ++r) {
        const float v = fmaxf(acc[mi][r], 0.f);
        const int off = ((mi * 4 + qt) * 64 + swz(rbase + r + 16 * sub)) * 8 + et;
        short s1, s2; split2(v, s1, s2);
        f[off] = s1; f[PLANE + off] = s2;
      }
  } else {
    float* __restrict__ hb = (float*)out;
#pragma unroll
    for (int mi = 0; mi < MTN; ++mi)
#pragma unroll
      for (int r = 0; r < 4; ++r)
        hb[(16 * mi + rbase + r) * kHRow + colg] = fmaxf(acc[mi][r], 0.f);
  }
}

__global__ __launch_bounds__(kThreads, 4) void fused_kernel(
    const float* __restrict__ x,
    const float* __restrict__ ewin, const float* __restrict__ ebin,
    const float* __restrict__ ebh,
    const float* __restrict__ ewout,const float* __restrict__ ebout,
    const float* __restrict__ dwin, const float* __restrict__ dbin,
    const float* __restrict__ dbh,
    const float* __restrict__ dwout,const float* __restrict__ dbout,
    const short* __restrict__ wfrag,
    float* __restrict__ y_g, float* __restrict__ xae_g,
    float* __restrict__ xadv_g, float* __restrict__ yadv_g)
{
  __shared__ __align__(16) char bufA[50688];
  __shared__ __align__(16) char bufB[50688];
  __shared__ __align__(16) double dmdS[5280];
  __shared__ float ybuf[512];
  __shared__ float yadv2[256];
  __shared__ float xstash[192];

  double* P    = dmdS;          // [32][67]
  double* Corr = dmdS + 2144;   // [32][33]
  double* KTm  = dmdS + 3200;   // [31][33]
  double* Dv   = dmdS + 4223;   // [32][33]

  short* fragA_G1 = (short*)bufA;               // 32768 B (dec G1 frag, 2 planes)
  short* fragA_G2 = (short*)(bufA + 32768);     // 16384 B (dec G2 frag, 2 planes)
  short* fragB_G1 = (short*)bufB;
  short* fragB_G2 = (short*)(bufB + 33792);     // after hbB G1 region
  float* hbB_G1   = (float*)bufB;               // [64][132] f32
  float* hbA_G2   = (float*)bufA;               // [32][132] f32

  const int tid = threadIdx.x;
  const int l64 = tid & 63;
  const int b = blockIdx.x;

  // ======== ph1: encoder input layer 3 -> 128, scatter-frag into bufA ========
  {
    constexpr int PE = 4 * 4 * 64 * 8;
    short* __restrict__ f = (short*)bufA;
    const float* __restrict__ xg = x + (size_t)b * kT * kPhys;
    const int j = tid & 127, rg = tid >> 7;  // 8 groups x 8 rows
    const float w0 = ewin[j], w1 = ewin[kNN + j], w2 = ewin[2 * kNN + j];
    const float bj = ebin[j];
    const int qt = j >> 5, sub = (j >> 3) & 3, et = j & 7;
#pragma unroll
    for (int rr = 0; rr < 8; ++rr) {
      const int r = rg * 8 + rr;
      const float* __restrict__ xr = xg + r * 3;
      const float a = fmaxf(bj + xr[0] * w0 + xr[1] * w1 + xr[2] * w2, 0.f);
      short s1, s2, s3; split3(a, s1, s2, s3);
      const int off = (((r >> 4) * 4 + qt) * 64 + swz((r & 15) + 16 * sub)) * 8 + et;
      f[off] = s1; f[PE + off] = s2; f[2 * PE + off] = s3;
    }
  }
  __syncthreads();

  // ======== ph2-4: encoder hidden layers (3-split, f32-exact) ========
  mfma_enc<2, 3, true >(wfrag + (size_t)0 * kWUnit, ebh + 0 * kNN, (short*)bufA, bufB, tid);
  __syncthreads();
  mfma_enc<2, 3, true >(wfrag + (size_t)3 * kWUnit, ebh + 1 * kNN, (short*)bufB, bufA, tid);
  __syncthreads();
  mfma_enc<2, 3, false>(wfrag + (size_t)6 * kWUnit, ebh + 2 * kNN, (short*)bufA, bufB, tid);
  __syncthreads();

  // ======== ph5: encoder output layer 128 -> 8 -> ybuf (no global store) ========
  if (tid < 512) {
    const float* __restrict__ hb = (const float*)bufB;
    const int r = tid >> 3, o = tid & 7;
    float a = ebout[o];
    for (int k4 = 0; k4 < kNN; k4 += 4) {
      const float4 hv = *(const float4*)&hb[r * kHRow + k4];
      a += hv.x * ewout[(k4 + 0) * kLat + o] + hv.y * ewout[(k4 + 1) * kLat + o]
         + hv.z * ewout[(k4 + 2) * kLat + o] + hv.w * ewout[(k4 + 3) * kLat + o];
    }
    ybuf[tid] = a;
  }
  __syncthreads();

  // ======== ph6: P (tid<512) || dec input scatter rows 0..63 (tid>=512) ========
  if (tid < 512) {
    for (int idx = tid; idx < 32 * 64; idx += 512) {
      const int d = idx >> 6, t = idx & 63;
      if (t + d < kT) {
        double s = 0.0;
#pragma unroll
        for (int l = 0; l < kLat; ++l)
          s += (double)ybuf[t * 8 + l] * (double)ybuf[(t + d) * 8 + l];
        P[d * 67 + t] = s;
      }
    }
  } else {
    constexpr int PD = 4 * 4 * 64 * 8;
    short* __restrict__ f = fragA_G1;
    const int j = tid & 127, rg = (tid >> 7) - 4;  // 4 groups x 16 rows
    float wr[kLat];
#pragma unroll
    for (int k = 0; k < kLat; ++k) wr[k] = dwin[k * kNN + j];
    const float bj = dbin[j];
    const int qt = j >> 5, sub = (j >> 3) & 3, et = j & 7;
#pragma unroll
    for (int rr = 0; rr < 16; ++rr) {
      const int r = rg * 16 + rr;  // 0..63
      const float* __restrict__ src = &ybuf[r * kLat];
      float a = bj;
#pragma unroll
      for (int k = 0; k < kLat; ++k) a += src[k] * wr[k];
      a = fmaxf(a, 0.f);
      short s1, s2; split2(a, s1, s2);
      const int off = (((r >> 4) * 4 + qt) * 64 + swz((r & 15) + 16 * sub)) * 8 + et;
      f[off] = s1; f[PD + off] = s2;
    }
  }
  __syncthreads();

  // ======== ph7: Corr ========
  {
    const int a = tid >> 5, c = tid & 31;
    const int d = (c >= a) ? (c - a) : (a - c);
    const int base = (c >= a) ? a : c;
    double s0 = 0.0, s1 = 0.0;
#pragma unroll
    for (int r = 0; r < 32; r += 2) { s0 += P[d * 67 + base + r]; s1 += P[d * 67 + base + r + 1]; }
    Corr[a * 33 + c] = s0 + s1 + P[d * 67 + base + 32];
  }
  __syncthreads();

  // ======== ph8: GJ+power (wave 0) || dec L0 G1 (waves 8..15) ========
  if (tid < 64) {
    const int lane = tid;
    const int colidx = (lane <= 30) ? lane : (lane <= 61 ? lane - 30 : 1);
    double m[31];
#pragma unroll
    for (int i = 0; i < 31; ++i) m[i] = Corr[i * 33 + colidx];
#pragma unroll
    for (int k = 0; k < 31; ++k) {
      const double piv = rdlane_f64(m[k], k);
      const double pinv = 1.0 / piv;
      m[k] *= pinv;
#pragma unroll
      for (int i = 0; i < 31; ++i) {
        if (i == k) continue;
        const double bci = rdlane_f64(m[i], k);
        m[i] = fma(-bci, m[k], m[i]);
      }
    }
    if (lane >= 31 && lane < 62) {
      const int c = lane - 31;
#pragma unroll
      for (int i = 0; i < 31; ++i) KTm[i * 33 + c] = m[i];
    }
    const int ri = (lane < 31) ? lane : 0;
    double Kr[31];
#pragma unroll
    for (int j = 0; j < 31; ++j) Kr[j] = KTm[ri * 33 + j];
    double dv = Kr[30];  // d_0 = K[:,30]
    if (lane < 31) Dv[0 * 33 + lane] = dv;
    for (int k = 0; k < 31; ++k) {
      double a0 = 0.0, a1 = 0.0, a2 = 0.0, a3 = 0.0;
#pragma unroll
      for (int j = 0; j < 31; ++j) {
        const double dj = rdlane_f64(dv, j);
        if ((j & 3) == 0) a0 = fma(Kr[j], dj, a0);
        else if ((j & 3) == 1) a1 = fma(Kr[j], dj, a1);
        else if ((j & 3) == 2) a2 = fma(Kr[j], dj, a2);
        else a3 = fma(Kr[j], dj, a3);
      }
      dv = (a0 + a1) + (a2 + a3);
      if (lane < 31) Dv[(k + 1) * 33 + lane] = dv;
    }
  } else if (tid >= 512) {
    mfma_dec<4, true>(wfrag + (size_t)9 * kWUnit, dbh + 0 * kNN,
                      fragA_G1, fragB_G1, (tid >> 6) - 8, l64);
  }
  __syncthreads();

  // ======== ph9: yadv2 (tid 512..767) || dec L1 G1 (waves 0..7) ========
  if (tid < 512) {
    mfma_dec<4, true>(wfrag + (size_t)11 * kWUnit, dbh + 1 * kNN,
                      fragB_G1, fragA_G1, tid >> 6, l64);
  } else if (tid < 768) {
    const int q = tid - 512;
    const int k = q >> 3, l = q & 7;
    double a0 = 0.0, a1 = 0.0, a2 = 0.0, a3 = 0.0;
#pragma unroll
    for (int j = 0; j < 31; ++j) {
      const double t = (double)ybuf[(j + 1) * 8 + l];
      if ((j & 3) == 0) a0 = fma(t, Dv[k * 33 + j], a0);
      else if ((j & 3) == 1) a1 = fma(t, Dv[k * 33 + j], a1);
      else if ((j & 3) == 2) a2 = fma(t, Dv[k * 33 + j], a2);
      else a3 = fma(t, Dv[k * 33 + j], a3);
    }
    yadv2[q] = (float)((a0 + a1) + (a2 + a3));
  }
  __syncthreads();

  // ======== ph10: dec scatter rows 64..95 (tid>=512) || dec L2 G1 (waves 0..7) ========
  if (tid < 512) {
    mfma_dec<4, false>(wfrag + (size_t)13 * kWUnit, dbh + 2 * kNN,
                       fragA_G1, hbB_G1, tid >> 6, l64);
  } else {
    constexpr int PD = 2 * 4 * 64 * 8;
    short* __restrict__ f = fragA_G2;
    const int j = tid & 127, rg = (tid >> 7) - 4;  // 4 groups x 8 rows
    float wr[kLat];
#pragma unroll
    for (int k = 0; k < kLat; ++k) wr[k] = dwin[k * kNN + j];
    const float bj = dbin[j];
    const int qt = j >> 5, sub = (j >> 3) & 3, et = j & 7;
#pragma unroll
    for (int rr = 0; rr < 8; ++rr) {
      const int r = 64 + rg * 8 + rr;  // 64..95
      const float* __restrict__ src = &yadv2[(r - kT) * kLat];
      float a = bj;
#pragma unroll
      for (int k = 0; k < kLat; ++k) a += src[k] * wr[k];
      a = fmaxf(a, 0.f);
      short s1, s2; split2(a, s1, s2);
      const int mi = (r - 64) >> 4;
      const int off = ((mi * 4 + qt) * 64 + swz((r & 15) + 16 * sub)) * 8 + et;
      f[off] = s1; f[PD + off] = s2;
    }
  }
  __syncthreads();

  // ======== ph11: dec out G1 -> xstash (tid<192) || dec L0 G2 (waves 8..15) ========
  if (tid < 192) {
    const int r = tid / 3, o = tid - r * 3;
    float a = dbout[o];
    for (int k4 = 0; k4 < kNN; k4 += 4) {
      const float4 hv = *(const float4*)&hbB_G1[r * kHRow + k4];
      a += hv.x * dwout[(k4 + 0) * kPhys + o] + hv.y * dwout[(k4 + 1) * kPhys + o]
         + hv.z * dwout[(k4 + 2) * kPhys + o] + hv.w * dwout[(k4 + 3) * kPhys + o];
    }
    xstash[tid] = a;
  } else if (tid >= 512) {
    mfma_dec<2, true>(wfrag + (size_t)9 * kWUnit, dbh + 0 * kNN,
                      fragA_G2, fragB_G2, (tid >> 6) - 8, l64);
  }
  __syncthreads();

  // ======== ph12: y/yadv global stores (tid<512) || dec L1 G2 (waves 8..15) ========
  if (tid < 512) {
    y_g[(size_t)b * kT * kLat + tid] = ybuf[tid];
    yadv_g[(size_t)b * kPred * kLat + tid] = (tid < 256) ? ybuf[tid] : yadv2[tid - 256];
  } else {
    mfma_dec<2, true>(wfrag + (size_t)11 * kWUnit, dbh + 1 * kNN,
                      fragB_G2, fragA_G2, (tid >> 6) - 8, l64);
  }
  __syncthreads();

  // ======== ph13: dec L2 G2 -> hbA (waves 0..7) ========
  if (tid < 512) {
    mfma_dec<2, false>(wfrag + (size_t)13 * kWUnit, dbh + 2 * kNN,
                       fragA_G2, hbA_G2, tid >> 6, l64);
  }
  __syncthreads();

  // ======== ph14 (final, no barrier): G2 out + x stores ========
  if (tid < 96) {
    const int r = tid / 3, o = tid - r * 3;  // local row 0..31 (global 64+r)
    float a = dbout[o];
    for (int k4 = 0; k4 < kNN; k4 += 4) {
      const float4 hv = *(const float4*)&hbA_G2[r * kHRow + k4];
      a += hv.x * dwout[(k4 + 0) * kPhys + o] + hv.y * dwout[(k4 + 1) * kPhys + o]
         + hv.z * dwout[(k4 + 2) * kPhys + o] + hv.w * dwout[(k4 + 3) * kPhys + o];
    }
    xadv_g[(size_t)b * kT * kPhys + (r + 32) * kPhys + o] = a;
  } else if (tid < 288) {
    const int i = tid - 96;
    xae_g[(size_t)b * kT * kPhys + i] = xstash[i];
  } else if (tid < 384) {
    const int i = tid - 288;
    xadv_g[(size_t)b * kT * kPhys + i] = xstash[i];
  }
}

extern "C" void kernel_launch(void* const* d_in, const int* in_sizes, int n_in,
                              void* d_out, int out_size, void* d_ws, size_t ws_size,
                              hipStream_t stream)
{
  const float* x         = (const float*)d_in[0];
  const float* enc_w_in  = (const float*)d_in[1];
  const float* enc_b_in  = (const float*)d_in[2];
  const float* enc_w_h   = (const float*)d_in[3];
  const float* enc_b_h   = (const float*)d_in[4];
  const float* enc_w_out = (const float*)d_in[5];
  const float* enc_b_out = (const float*)d_in[6];
  const float* dec_w_in  = (const float*)d_in[7];
  const float* dec_b_in  = (const float*)d_in[8];
  const float* dec_w_h   = (const float*)d_in[9];
  const float* dec_b_h   = (const float*)d_in[10];
  const float* dec_w_out = (const float*)d_in[11];
  const float* dec_b_out = (const float*)d_in[12];

  float* out   = (float*)d_out;
  float* y     = out;                                  // (B,T,8)   131072
  float* x_ae  = out + (size_t)kB * kT * kLat;         // (B,T,3)    49152
  float* x_adv = x_ae + (size_t)kB * kT * kPhys;       // (B,T,3)    49152
  float* y_adv = x_adv + (size_t)kB * kT * kPhys;      // (B,64,8)  131072

  short* wfrag = (short*)d_ws;   // 15 units x 16384 shorts = 491520 B

  split_weights_kernel<<<48, 256, 0, stream>>>(enc_w_h, dec_w_h, wfrag);
  fused_kernel<<<kB, kThreads, 0, stream>>>(
      x, enc_w_in, enc_b_in, enc_b_h, enc_w_out, enc_b_out,
      dec_w_in, dec_b_in, dec_b_h, dec_w_out, dec_b_out,
      wfrag, y, x_ae, x_adv, y_adv);
}